// Round 6
// baseline (536.399 us; speedup 1.0000x reference)
//
#include <hip/hip_runtime.h>
#include <hip/hip_bf16.h>
#include <math.h>

typedef __attribute__((ext_vector_type(8))) short short8;
typedef __attribute__((ext_vector_type(4))) float f32x4;

__device__ __forceinline__ unsigned short f2bf(float x) {
    __hip_bfloat16 b = __float2bfloat16(x);
    return *reinterpret_cast<unsigned short*>(&b);
}
__device__ __forceinline__ float bfu2f(unsigned short u) {
    union { unsigned u; float f; } c; c.u = ((unsigned)u) << 16; return c.f;
}
__device__ __forceinline__ float gelu_exact(float x) {
    return 0.5f * x * (1.0f + erff(x * 0.70710678118654752f));
}

// ---------------------------------------------------------------- zero
__global__ __launch_bounds__(256) void k_zero(float* __restrict__ p, long n)
{
    long i = (long)blockIdx.x * 256 + threadIdx.x;
    if (i < n) p[i] = 0.f;
}

// ---------------------------------------------------------------- layernorm (standalone, pre-loop)
__global__ __launch_bounds__(256) void k_layernorm(
    const float* __restrict__ x, const float* __restrict__ g,
    const float* __restrict__ b, float* __restrict__ out)
{
    int wave = threadIdx.x >> 6, lane = threadIdx.x & 63;
    long row = (long)blockIdx.x * 4 + wave;
    float v = x[row * 64 + lane];
    float s = v;
    #pragma unroll
    for (int o = 32; o; o >>= 1) s += __shfl_xor(s, o);
    float m = s * (1.0f / 64.0f);
    float d = v - m;
    float q = d * d;
    #pragma unroll
    for (int o = 32; o; o >>= 1) q += __shfl_xor(q, o);
    float rstd = rsqrtf(q * (1.0f / 64.0f) + 1e-5f);
    out[row * 64 + lane] = d * rstd * g[lane] + b[lane];
}

// ---------------------------------------------------------------- Wfold[l] = Wqkv_v[l] @ Wout[l]
__global__ __launch_bounds__(256) void k_wfold2(
    const float* __restrict__ Wqkv, const float* __restrict__ Wout,
    float* __restrict__ Wfold)   // [2][64][64]
{
    int idx = blockIdx.x * 256 + threadIdx.x;   // 8192
    int l = idx >> 12, rem = idx & 4095;
    int c = rem >> 6, d = rem & 63;
    const float* Wq = Wqkv + (long)l * 49152;
    const float* Wo = Wout + (long)l * 16384;
    float a = 0.f;
    for (int k = 0; k < 256; ++k)
        a += Wq[c * 768 + 512 + k] * Wo[k * 64 + d];
    Wfold[idx] = a;
}

// ---------------------------------------------------------------- mask pack: bit j = A[row][j] > 0
__global__ __launch_bounds__(256) void k_maskpack(
    const float* __restrict__ Aadj, unsigned long long* __restrict__ mask)
{
    int row = blockIdx.x;
    int wave = threadIdx.x >> 6, lane = threadIdx.x & 63;
    for (int w = wave; w < 64; w += 4) {
        float a = Aadj[(long)row * 4096 + w * 64 + lane];
        unsigned long long m = __ballot(a > 0.f);
        if (lane == 0) mask[(long)row * 64 + w] = m;
    }
}

// ---------------------------------------------------------------- fused q,k (y<8) + vWT (y>=8)
// q|k[4096,256]bf16 = xn_b0 @ Wqkv[:,0:512] ; vWT[b*64+d][n]bf16 = xn_b @ Wfold
__global__ __launch_bounds__(256) void k_qkxnw(
    const float* __restrict__ xn, const float* __restrict__ W,
    const float* __restrict__ Wfold,
    unsigned short* __restrict__ q, unsigned short* __restrict__ kmat,
    unsigned short* __restrict__ vwt)
{
    __shared__ float As[64][65];
    __shared__ float Ws[64][65];
    int tid = threadIdx.x;
    int y = blockIdx.y;
    int qk = (y < 8);
    int m0, b = 0, n0;
    if (qk) { m0 = blockIdx.x * 64; n0 = y * 64; }
    else    { b = y - 8; m0 = b * 4096 + blockIdx.x * 64; n0 = 0; }
    #pragma unroll
    for (int it = 0; it < 16; ++it) {
        int idx = tid + it * 256;
        int r = idx >> 6, c = idx & 63;
        As[r][c] = xn[(long)(m0 + r) * 64 + c];
        Ws[r][c] = qk ? W[(long)r * 768 + n0 + c] : Wfold[r * 64 + c];
    }
    __syncthreads();
    int tx = tid & 15, ty = tid >> 4;
    float acc[4][4] = {};
    #pragma unroll
    for (int k = 0; k < 64; ++k) {
        float a[4], w[4];
        #pragma unroll
        for (int i = 0; i < 4; ++i) a[i] = As[ty * 4 + i][k];
        #pragma unroll
        for (int j = 0; j < 4; ++j) w[j] = Ws[k][tx * 4 + j];
        #pragma unroll
        for (int i = 0; i < 4; ++i)
            #pragma unroll
            for (int j = 0; j < 4; ++j) acc[i][j] += a[i] * w[j];
    }
    if (qk) {
        #pragma unroll
        for (int i = 0; i < 4; ++i) {
            long row = m0 + ty * 4 + i;
            #pragma unroll
            for (int j = 0; j < 4; ++j) {
                int col = n0 + tx * 4 + j;
                if (col < 256) q[row * 256 + col] = f2bf(acc[i][j]);
                else           kmat[row * 256 + (col - 256)] = f2bf(acc[i][j]);
            }
        }
    } else {
        int nb = blockIdx.x * 64;
        #pragma unroll
        for (int i = 0; i < 4; ++i)
            #pragma unroll
            for (int j = 0; j < 4; ++j)
                vwt[((long)b * 64 + tx * 4 + j) * 4096 + nb + ty * 4 + i] = f2bf(acc[i][j]);
    }
}

// ---------------------------------------------------------------- dots GEMM (NT)
// C[4096,4096] = 0.125 * q @ k^T ; K=256; out bf16 (Ch) or fp32 (Cf)
__global__ __launch_bounds__(256) void k_dots(
    const unsigned short* __restrict__ A, const unsigned short* __restrict__ B,
    unsigned short* __restrict__ Ch, float* __restrict__ Cf)
{
    __shared__ __align__(16) unsigned short As[128 * 64];
    __shared__ __align__(16) unsigned short Bs[128 * 64];
    const int K = 256;
    int tid = threadIdx.x;
    int lane = tid & 63, wave = tid >> 6;
    long m0 = (long)blockIdx.x * 128, n0 = (long)blockIdx.y * 128;
    const unsigned short* Ag = A + m0 * K;
    const unsigned short* Bg = B + n0 * K;
    int wm = (wave & 1) * 64, wn = (wave >> 1) * 64;
    int fr = lane & 15, quad = lane >> 4;

    f32x4 acc[4][4];
    #pragma unroll
    for (int i = 0; i < 4; ++i)
        #pragma unroll
        for (int j = 0; j < 4; ++j) acc[i][j] = (f32x4){0.f, 0.f, 0.f, 0.f};

    for (int k0 = 0; k0 < K; k0 += 64) {
        #pragma unroll
        for (int it = 0; it < 4; ++it) {
            int c = tid + it * 256;
            int r = c >> 3, col = (c & 7) * 8;
            *(short8*)&As[c * 8] = *(const short8*)(Ag + (long)r * K + k0 + col);
            *(short8*)&Bs[c * 8] = *(const short8*)(Bg + (long)r * K + k0 + col);
        }
        __syncthreads();
        #pragma unroll
        for (int ks = 0; ks < 2; ++ks) {
            short8 af[4], bfr[4];
            #pragma unroll
            for (int i = 0; i < 4; ++i) {
                af[i]  = *(const short8*)&As[(wm + i * 16 + fr) * 64 + ks * 32 + quad * 8];
                bfr[i] = *(const short8*)&Bs[(wn + i * 16 + fr) * 64 + ks * 32 + quad * 8];
            }
            #pragma unroll
            for (int i = 0; i < 4; ++i)
                #pragma unroll
                for (int j = 0; j < 4; ++j)
                    acc[i][j] = __builtin_amdgcn_mfma_f32_16x16x32_bf16(
                        af[i], bfr[j], acc[i][j], 0, 0, 0);
        }
        __syncthreads();
    }
    #pragma unroll
    for (int i = 0; i < 4; ++i) {
        #pragma unroll
        for (int j = 0; j < 4; ++j) {
            long col = n0 + wn + j * 16 + fr;
            long rowb = m0 + wm + i * 16 + quad * 4;
            #pragma unroll
            for (int r = 0; r < 4; ++r) {
                float v = acc[i][j][r] * 0.125f;
                if (Ch) Ch[(rowb + r) * 4096 + col] = f2bf(v);
                else    Cf[(rowb + r) * 4096 + col] = v;
            }
        }
    }
}

// ---------------------------------------------------------------- attn@vWT split-K GEMM
// C[4096,128] += A[4096,4096] @ B[128,4096]^T ; A bf16 (Ah) or fp32-convert (Af)
// grid (32 m-tiles, 8 k-chunks of 512); device-scope atomicAdd accumulate.
__global__ __launch_bounds__(256) void k_splitk(
    const unsigned short* __restrict__ Ah, const float* __restrict__ Af,
    const unsigned short* __restrict__ B, float* __restrict__ C)
{
    __shared__ __align__(16) unsigned short As[128 * 64];
    __shared__ __align__(16) unsigned short Bs[128 * 64];
    const int K = 4096, N = 128;
    int tid = threadIdx.x;
    int lane = tid & 63, wave = tid >> 6;
    long m0 = (long)blockIdx.x * 128;
    int k0base = blockIdx.y * 512;
    int wm = (wave & 1) * 64, wn = (wave >> 1) * 64;
    int fr = lane & 15, quad = lane >> 4;

    f32x4 acc[4][4];
    #pragma unroll
    for (int i = 0; i < 4; ++i)
        #pragma unroll
        for (int j = 0; j < 4; ++j) acc[i][j] = (f32x4){0.f, 0.f, 0.f, 0.f};

    for (int k0 = k0base; k0 < k0base + 512; k0 += 64) {
        #pragma unroll
        for (int it = 0; it < 4; ++it) {
            int c = tid + it * 256;
            int r = c >> 3, col = (c & 7) * 8;
            if (Ah) {
                *(short8*)&As[c * 8] =
                    *(const short8*)(Ah + (m0 + r) * (long)K + k0 + col);
            } else {
                const float* Ag = Af + m0 * K;
                float4 f0 = *(const float4*)(Ag + (long)r * K + k0 + col);
                float4 f1 = *(const float4*)(Ag + (long)r * K + k0 + col + 4);
                short8 s;
                s[0] = (short)f2bf(f0.x); s[1] = (short)f2bf(f0.y);
                s[2] = (short)f2bf(f0.z); s[3] = (short)f2bf(f0.w);
                s[4] = (short)f2bf(f1.x); s[5] = (short)f2bf(f1.y);
                s[6] = (short)f2bf(f1.z); s[7] = (short)f2bf(f1.w);
                *(short8*)&As[c * 8] = s;
            }
            *(short8*)&Bs[c * 8] = *(const short8*)(B + (long)r * K + k0 + col);
        }
        __syncthreads();
        #pragma unroll
        for (int ks = 0; ks < 2; ++ks) {
            short8 af[4], bfr[4];
            #pragma unroll
            for (int i = 0; i < 4; ++i) {
                af[i]  = *(const short8*)&As[(wm + i * 16 + fr) * 64 + ks * 32 + quad * 8];
                bfr[i] = *(const short8*)&Bs[(wn + i * 16 + fr) * 64 + ks * 32 + quad * 8];
            }
            #pragma unroll
            for (int i = 0; i < 4; ++i)
                #pragma unroll
                for (int j = 0; j < 4; ++j)
                    acc[i][j] = __builtin_amdgcn_mfma_f32_16x16x32_bf16(
                        af[i], bfr[j], acc[i][j], 0, 0, 0);
        }
        __syncthreads();
    }
    #pragma unroll
    for (int i = 0; i < 4; ++i) {
        #pragma unroll
        for (int j = 0; j < 4; ++j) {
            long col = wn + j * 16 + fr;
            long rowb = m0 + wm + i * 16 + quad * 4;
            #pragma unroll
            for (int r = 0; r < 4; ++r)
                atomicAdd(&C[(rowb + r) * N + col], acc[i][j][r]);
        }
    }
}

// ---------------------------------------------------------------- block reduce helpers
__device__ __forceinline__ float block_max(float v, float* red, int lane, int wave) {
    #pragma unroll
    for (int o = 32; o; o >>= 1) v = fmaxf(v, __shfl_xor(v, o));
    if (lane == 0) red[wave] = v;
    __syncthreads();
    v = fmaxf(fmaxf(red[0], red[1]), fmaxf(red[2], red[3]));
    __syncthreads();
    return v;
}
__device__ __forceinline__ float block_sum(float v, float* red, int lane, int wave) {
    #pragma unroll
    for (int o = 32; o; o >>= 1) v += __shfl_xor(v, o);
    if (lane == 0) red[wave] = v;
    __syncthreads();
    v = red[0] + red[1] + red[2] + red[3];
    __syncthreads();
    return v;
}

// ---------------------------------------------------------------- softmax on bf16 dots
// thread t holds row cols [t*16, t*16+16). masked softmax -> attn_h (may ALIAS dots:
// full row read to regs before writes, block-local). Optional attn_f (fp32) and
// ds (fp32, unmasked softmax of raw dots).
__global__ __launch_bounds__(256) void k_softmax_bf(
    const unsigned short* __restrict__ dots, const unsigned long long* __restrict__ mask,
    unsigned short* __restrict__ attn_h, float* __restrict__ attn_f,
    float* __restrict__ ds)
{
    __shared__ float red[4];
    int row = blockIdx.x, tid = threadIdx.x;
    int lane = tid & 63, wave = tid >> 6;
    long base = (long)row * 4096 + tid * 16;
    short8 v0 = *(const short8*)(dots + base);
    short8 v1 = *(const short8*)(dots + base + 8);
    unsigned long long mw = mask[(long)row * 64 + (tid >> 2)];
    int mbase = (tid & 3) * 16;
    int idiag = row - tid * 16;   // in [0,16) if this thread owns the diagonal
    float d[16], mv[16];
    float mmax = -1e30f, umax = -1e30f;
    #pragma unroll
    for (int i = 0; i < 16; ++i) {
        float dv = bfu2f((unsigned short)(i < 8 ? v0[i] : v1[i - 8]));
        d[i] = dv;
        float m = ((mw >> (mbase + i)) & 1ull) ? dv : -1e30f;
        if (i == idiag) m = 1.0f;
        mv[i] = m;
        mmax = fmaxf(mmax, m);
        umax = fmaxf(umax, dv);
    }
    float M1 = block_max(mmax, red, lane, wave);
    float s1 = 0.f;
    #pragma unroll
    for (int i = 0; i < 16; ++i) { float e = expf(mv[i] - M1); mv[i] = e; s1 += e; }
    s1 = block_sum(s1, red, lane, wave);
    float inv1 = 1.0f / s1;
    short8 o0, o1;
    #pragma unroll
    for (int i = 0; i < 16; ++i) {
        float p = mv[i] * inv1;
        mv[i] = p;
        if (i < 8) o0[i] = (short)f2bf(p); else o1[i - 8] = (short)f2bf(p);
    }
    *(short8*)(attn_h + base) = o0;
    *(short8*)(attn_h + base + 8) = o1;
    if (attn_f) {
        #pragma unroll
        for (int i = 0; i < 4; ++i)
            *(float4*)(attn_f + base + i * 4) =
                (float4){mv[i * 4], mv[i * 4 + 1], mv[i * 4 + 2], mv[i * 4 + 3]};
    }
    if (ds) {
        float M2 = block_max(umax, red, lane, wave);
        float s2 = 0.f;
        #pragma unroll
        for (int i = 0; i < 16; ++i) { float e = expf(d[i] - M2); d[i] = e; s2 += e; }
        s2 = block_sum(s2, red, lane, wave);
        float inv2 = 1.0f / s2;
        #pragma unroll
        for (int i = 0; i < 4; ++i)
            *(float4*)(ds + base + i * 4) =
                (float4){d[i * 4] * inv2, d[i * 4 + 1] * inv2,
                         d[i * 4 + 2] * inv2, d[i * 4 + 3] * inv2};
    }
}

// ---------------------------------------------------------------- softmax on fp32 dots (fallback l=1)
// reads fp32 dots, writes attn fp32 + ds fp32 IN PLACE over dots (block-local safe).
__global__ __launch_bounds__(256) void k_softmax_f32(
    float* __restrict__ dots, const unsigned long long* __restrict__ mask,
    float* __restrict__ attn_f)
{
    __shared__ float red[4];
    int row = blockIdx.x, tid = threadIdx.x;
    int lane = tid & 63, wave = tid >> 6;
    long base = (long)row * 4096 + tid * 16;
    float d[16], mv[16];
    #pragma unroll
    for (int i = 0; i < 4; ++i) {
        float4 f = *(const float4*)(dots + base + i * 4);
        d[i * 4] = f.x; d[i * 4 + 1] = f.y; d[i * 4 + 2] = f.z; d[i * 4 + 3] = f.w;
    }
    unsigned long long mw = mask[(long)row * 64 + (tid >> 2)];
    int mbase = (tid & 3) * 16;
    int idiag = row - tid * 16;
    float mmax = -1e30f, umax = -1e30f;
    #pragma unroll
    for (int i = 0; i < 16; ++i) {
        float m = ((mw >> (mbase + i)) & 1ull) ? d[i] : -1e30f;
        if (i == idiag) m = 1.0f;
        mv[i] = m;
        mmax = fmaxf(mmax, m);
        umax = fmaxf(umax, d[i]);
    }
    float M1 = block_max(mmax, red, lane, wave);
    float s1 = 0.f;
    #pragma unroll
    for (int i = 0; i < 16; ++i) { float e = expf(mv[i] - M1); mv[i] = e; s1 += e; }
    s1 = block_sum(s1, red, lane, wave);
    float inv1 = 1.0f / s1;
    #pragma unroll
    for (int i = 0; i < 4; ++i)
        *(float4*)(attn_f + base + i * 4) =
            (float4){mv[i * 4] * inv1, mv[i * 4 + 1] * inv1,
                     mv[i * 4 + 2] * inv1, mv[i * 4 + 3] * inv1};
    float M2 = block_max(umax, red, lane, wave);
    float s2 = 0.f;
    #pragma unroll
    for (int i = 0; i < 16; ++i) { float e = expf(d[i] - M2); d[i] = e; s2 += e; }
    s2 = block_sum(s2, red, lane, wave);
    float inv2 = 1.0f / s2;
    #pragma unroll
    for (int i = 0; i < 4; ++i)
        *(float4*)(dots + base + i * 4) =
            (float4){d[i * 4] * inv2, d[i * 4 + 1] * inv2,
                     d[i * 4 + 2] * inv2, d[i * 4 + 3] * inv2};
}

// ---------------------------------------------------------------- fused tail:
// x = xn + avcat + bout ; xm = LN(x,g2,b2) ; h = gelu(xm@W1+bb1) ;
// x2 = xm + h@W2 + bb2 ; out = LN(x2, gn, bn)    (all in LDS; one 64-row tile/block)
__global__ __launch_bounds__(256) void k_tail(
    const float* __restrict__ xn, const float* __restrict__ avcat,
    const float* __restrict__ bout,
    const float* __restrict__ g2, const float* __restrict__ b2,
    const float* __restrict__ W1, const float* __restrict__ bb1,
    const float* __restrict__ W2, const float* __restrict__ bb2,
    const float* __restrict__ gn, const float* __restrict__ bn,
    float* __restrict__ out)
{
    __shared__ float X[64][65], XM[64][65], H[64][65], WS[64][65];
    int tid = threadIdx.x;
    int m0 = blockIdx.x * 64;
    int wv = tid >> 6, ln = tid & 63;
    // phase 1: x = xn + avcat(reindex) + bout
    #pragma unroll
    for (int it = 0; it < 16; ++it) {
        int idx = tid + it * 256;
        int r = idx >> 6, c = idx & 63;
        int gr = m0 + r;
        X[r][c] = xn[(long)gr * 64 + c]
                + avcat[(long)(gr & 4095) * 128 + (gr >> 12) * 64 + c]
                + bout[c];
    }
    __syncthreads();
    // LN2 -> XM
    #pragma unroll
    for (int rr = 0; rr < 16; ++rr) {
        int r = wv * 16 + rr;
        float v = X[r][ln];
        float s = v;
        #pragma unroll
        for (int o = 32; o; o >>= 1) s += __shfl_xor(s, o);
        float m = s * (1.0f / 64.0f);
        float dd = v - m;
        float q = dd * dd;
        #pragma unroll
        for (int o = 32; o; o >>= 1) q += __shfl_xor(q, o);
        float rstd = rsqrtf(q * (1.0f / 64.0f) + 1e-5f);
        XM[r][ln] = dd * rstd * g2[ln] + b2[ln];
    }
    __syncthreads();
    // W1 -> WS
    #pragma unroll
    for (int it = 0; it < 16; ++it) {
        int idx = tid + it * 256;
        WS[idx >> 6][idx & 63] = W1[idx];
    }
    __syncthreads();
    int tx = tid & 15, ty = tid >> 4;
    {
        float acc[4][4] = {};
        #pragma unroll
        for (int k = 0; k < 64; ++k) {
            float a[4], w[4];
            #pragma unroll
            for (int i = 0; i < 4; ++i) a[i] = XM[ty * 4 + i][k];
            #pragma unroll
            for (int j = 0; j < 4; ++j) w[j] = WS[k][tx * 4 + j];
            #pragma unroll
            for (int i = 0; i < 4; ++i)
                #pragma unroll
                for (int j = 0; j < 4; ++j) acc[i][j] += a[i] * w[j];
        }
        #pragma unroll
        for (int i = 0; i < 4; ++i)
            #pragma unroll
            for (int j = 0; j < 4; ++j)
                H[ty * 4 + i][tx * 4 + j] = gelu_exact(acc[i][j] + bb1[tx * 4 + j]);
    }
    __syncthreads();
    // W2 -> WS
    #pragma unroll
    for (int it = 0; it < 16; ++it) {
        int idx = tid + it * 256;
        WS[idx >> 6][idx & 63] = W2[idx];
    }
    __syncthreads();
    {
        float acc[4][4] = {};
        #pragma unroll
        for (int k = 0; k < 64; ++k) {
            float a[4], w[4];
            #pragma unroll
            for (int i = 0; i < 4; ++i) a[i] = H[ty * 4 + i][k];
            #pragma unroll
            for (int j = 0; j < 4; ++j) w[j] = WS[k][tx * 4 + j];
            #pragma unroll
            for (int i = 0; i < 4; ++i)
                #pragma unroll
                for (int j = 0; j < 4; ++j) acc[i][j] += a[i] * w[j];
        }
        #pragma unroll
        for (int i = 0; i < 4; ++i)
            #pragma unroll
            for (int j = 0; j < 4; ++j)
                X[ty * 4 + i][tx * 4 + j] =
                    XM[ty * 4 + i][tx * 4 + j] + acc[i][j] + bb2[tx * 4 + j];
    }
    __syncthreads();
    // LN_next -> out
    #pragma unroll
    for (int rr = 0; rr < 16; ++rr) {
        int r = wv * 16 + rr;
        float v = X[r][ln];
        float s = v;
        #pragma unroll
        for (int o = 32; o; o >>= 1) s += __shfl_xor(s, o);
        float m = s * (1.0f / 64.0f);
        float dd = v - m;
        float q = dd * dd;
        #pragma unroll
        for (int o = 32; o; o >>= 1) q += __shfl_xor(q, o);
        float rstd = rsqrtf(q * (1.0f / 64.0f) + 1e-5f);
        out[(long)(m0 + r) * 64 + ln] = dd * rstd * gn[ln] + bn[ln];
    }
}

// ---------------------------------------------------------------- launch
extern "C" void kernel_launch(void* const* d_in, const int* in_sizes, int n_in,
                              void* d_out, int out_size, void* d_ws, size_t ws_size,
                              hipStream_t stream)
{
    const float* embed = (const float*)d_in[0];
    const float* Aadj  = (const float*)d_in[1];
    const float* g1    = (const float*)d_in[2];
    const float* b1    = (const float*)d_in[3];
    const float* Wqkv  = (const float*)d_in[4];
    const float* Wout  = (const float*)d_in[5];
    const float* bout  = (const float*)d_in[6];
    const float* g2    = (const float*)d_in[7];
    const float* b2    = (const float*)d_in[8];
    const float* W1    = (const float*)d_in[9];
    const float* bb1   = (const float*)d_in[10];
    const float* W2    = (const float*)d_in[11];
    const float* bb2   = (const float*)d_in[12];
    const float* gf    = (const float*)d_in[13];
    const float* bff   = (const float*)d_in[14];

    // output regions (fp32): [x 2MB | attn 64MB | ds 64MB]
    float* ox    = (float*)d_out;
    float* attnb = ox + 524288;
    float* dsb   = attnb + 16777216;

    if (ws_size < (10ull << 20)) {           // diagnostic guard
        k_zero<<<133120, 256, 0, stream>>>(ox, 34078720l);
        return;
    }

    // ws layout: xn 2MB | avcat 2MB | q 1MB | k 1MB | vwt 1MB | Wfold2 32KB | mask 2MB | [wsbuf 32MB]
    char* ws = (char*)d_ws;
    float*          xn    = (float*)(ws + (0l << 20));
    float*          avcat = (float*)(ws + (2l << 20));
    unsigned short* q     = (unsigned short*)(ws + (4l << 20));
    unsigned short* kmat  = (unsigned short*)(ws + (5l << 20));
    unsigned short* vwt   = (unsigned short*)(ws + (6l << 20));
    float*          Wfold = (float*)(ws + (7l << 20));
    unsigned long long* mask = (unsigned long long*)(ws + (7l << 20) + 32768);
    unsigned short* wsbuf = (unsigned short*)(ws + (10l << 20));     // 32 MB, rich only
    bool rich = ws_size >= (42ull << 20);

    k_layernorm<<<2048, 256, 0, stream>>>(embed, g1, b1, xn);
    k_wfold2<<<32, 256, 0, stream>>>(Wqkv, Wout, Wfold);
    k_maskpack<<<4096, 256, 0, stream>>>(Aadj, mask);

    for (int l = 0; l < 2; ++l) {
        k_qkxnw<<<dim3(64, 10), 256, 0, stream>>>(xn, Wqkv + (long)l * 49152,
                                                  Wfold + l * 4096, q, kmat, vwt);
        if (rich) {
            // dots bf16 -> wsbuf; softmax in place (attn bf16); l==1 also attn fp32 + ds
            k_dots<<<dim3(32, 32), 256, 0, stream>>>(q, kmat, wsbuf, nullptr);
            k_softmax_bf<<<4096, 256, 0, stream>>>(wsbuf, mask, wsbuf,
                                                   l ? attnb : nullptr,
                                                   l ? dsb : nullptr);
            k_zero<<<2048, 256, 0, stream>>>(avcat, 524288l);
            k_splitk<<<dim3(32, 8), 256, 0, stream>>>(wsbuf, nullptr, vwt, avcat);
        } else if (l == 0) {
            // dots bf16 in dsb region; attn bf16 in attnb region (both free at l=0)
            unsigned short* dots_h = (unsigned short*)dsb;
            unsigned short* attn_h = (unsigned short*)attnb;
            k_dots<<<dim3(32, 32), 256, 0, stream>>>(q, kmat, dots_h, nullptr);
            k_softmax_bf<<<4096, 256, 0, stream>>>(dots_h, mask, attn_h,
                                                   nullptr, nullptr);
            k_zero<<<2048, 256, 0, stream>>>(avcat, 524288l);
            k_splitk<<<dim3(32, 8), 256, 0, stream>>>(attn_h, nullptr, vwt, avcat);
        } else {
            // dots fp32 in dsb; softmax writes attn fp32 + ds in place; splitk converts
            k_dots<<<dim3(32, 32), 256, 0, stream>>>(q, kmat, nullptr, dsb);
            k_softmax_f32<<<4096, 256, 0, stream>>>(dsb, mask, attnb);
            k_zero<<<2048, 256, 0, stream>>>(avcat, 524288l);
            k_splitk<<<dim3(32, 8), 256, 0, stream>>>(nullptr, attnb, vwt, avcat);
        }
        // fused residual + LN2 + MLP + LN(next or final)
        k_tail<<<128, 256, 0, stream>>>(xn, avcat, bout + 64 * l,
                                        g2 + 64 * l, b2 + 64 * l,
                                        W1 + (long)l * 4096, bb1 + 64 * l,
                                        W2 + (long)l * 4096, bb2 + 64 * l,
                                        l ? gf : g1 + 64, l ? bff : b1 + 64,
                                        l ? ox : xn);
    }
}